// Round 3
// baseline (1027.657 us; speedup 1.0000x reference)
//
#include <hip/hip_runtime.h>

#define NB 4
#define CHN 512
#define HWD 4096
#define LTOT (NB*HWD)
#define FEAT_ 256
#define POOL_ 8192

typedef __attribute__((ext_vector_type(8))) __bf16 bf16x8;
typedef __attribute__((ext_vector_type(8))) unsigned short u16x8;
typedef __attribute__((ext_vector_type(4))) float f32x4;

static __device__ __forceinline__ unsigned short f2bf(float f){
  union { float f; unsigned u; } c; c.f = f;
  unsigned u = c.u;
  u += 0x7fffu + ((u >> 16) & 1u);   // round-to-nearest-even
  return (unsigned short)(u >> 16);
}

static __device__ __forceinline__ f32x4 mfma16(bf16x8 a, bf16x8 b, f32x4 c){
  return __builtin_amdgcn_mfma_f32_16x16x32_bf16(a, b, c, 0, 0, 0);
}

static __device__ __forceinline__ bf16x8 ld_bf8(const void* p){
  u16x8 v = *(const u16x8*)p;
  return __builtin_bit_cast(bf16x8, v);
}

// ---------------- f32 -> bf16 convert (layout-preserving) ----------------
__global__ void k_cvt(const float* __restrict__ src, unsigned short* __restrict__ dst, int n4){
  int i = blockIdx.x * 256 + threadIdx.x;
  if (i < n4) {
    const float4 v = *(const float4*)(src + (size_t)i * 4);
    ushort4 o; o.x = f2bf(v.x); o.y = f2bf(v.y); o.z = f2bf(v.z); o.w = f2bf(v.w);
    *(ushort4*)(dst + (size_t)i * 4) = o;
  }
}

// ---------------- pool [256][8192] f32 -> poolKT [8192][256] bf16 (plain) ----------------
__global__ __launch_bounds__(256) void k_poolT(const float* __restrict__ pool,
                                               unsigned short* __restrict__ poolT){
  __shared__ float tile[32][33];
  int bf = blockIdx.x & 7;
  int bp = blockIdx.x >> 3;
  int t = threadIdx.x;
  int fi = t >> 3, j = (t & 7) * 4;
  const float4 v = *(const float4*)(pool + (size_t)(bf*32 + fi) * POOL_ + bp*32 + j);
  tile[fi][j+0] = v.x; tile[fi][j+1] = v.y; tile[fi][j+2] = v.z; tile[fi][j+3] = v.w;
  __syncthreads();
  int pi = t >> 3, fj = (t & 7) * 4;
  int p = bp*32 + pi;
  ushort4 o;
  o.x = f2bf(tile[fj+0][pi]); o.y = f2bf(tile[fj+1][pi]);
  o.z = f2bf(tile[fj+2][pi]); o.w = f2bf(tile[fj+3][pi]);
  *(ushort4*)((char*)poolT + (size_t)p * 512 + (bf*32 + fj) * 2) = o;
}

// ---------------- x [4][512][4096] f32 -> xT [4][4096][512] bf16 ----------------
__global__ __launch_bounds__(256) void k_xT(const float* __restrict__ x,
                                            unsigned short* __restrict__ xT){
  __shared__ float tile[32][33];
  int b = blockIdx.x;
  int lt = b & 127; int ct = (b >> 7) & 15; int n = b >> 11;
  int t = threadIdx.x;
  int fi = t >> 3, j = (t & 7) * 4;
  const float4 v = *(const float4*)(x + ((size_t)(n*CHN + ct*32 + fi)) * HWD + lt*32 + j);
  tile[fi][j+0] = v.x; tile[fi][j+1] = v.y; tile[fi][j+2] = v.z; tile[fi][j+3] = v.w;
  __syncthreads();
  int pi = t >> 3, fj = (t & 7) * 4;
  ushort4 o;
  o.x = f2bf(tile[fj+0][pi]); o.y = f2bf(tile[fj+1][pi]);
  o.z = f2bf(tile[fj+2][pi]); o.w = f2bf(tile[fj+3][pi]);
  *(ushort4*)((char*)xT + ((size_t)(n*HWD + lt*32 + pi)) * 1024 + (ct*32 + fj) * 2) = o;
}

// ---------------- theta GEMM: Q[l][f] = sum_c xT[l][c] * wt[f][c] ----------------
__global__ __launch_bounds__(256) void k_theta(const unsigned short* __restrict__ xT,
                                               const unsigned short* __restrict__ wt,
                                               unsigned short* __restrict__ Q){
  int w = threadIdx.x >> 6, lane = threadIdx.x & 63;
  int lq = lane & 15, hq = lane >> 4;
  int lbase = blockIdx.x * 64 + w * 16;
  const char* xb = (const char*)xT;
  const char* wb = (const char*)wt;
  f32x4 acc[16];
  #pragma unroll
  for (int i = 0; i < 16; ++i) acc[i] = {};
  #pragma unroll 2
  for (int kk = 0; kk < 16; ++kk) {
    bf16x8 a = ld_bf8(xb + (size_t)(lbase + lq) * 1024 + kk*64 + hq*16);
    #pragma unroll
    for (int fi = 0; fi < 16; ++fi) {
      bf16x8 bfr = ld_bf8(wb + (size_t)(fi*16 + lq) * 1024 + kk*64 + hq*16);
      acc[fi] = mfma16(a, bfr, acc[fi]);
    }
  }
  #pragma unroll
  for (int fi = 0; fi < 16; ++fi) {
    #pragma unroll
    for (int r = 0; r < 4; ++r) {
      int l = lbase + hq*4 + r;
      Q[(size_t)l * 256 + fi*16 + lq] = f2bf(acc[fi][r]);
    }
  }
}

// ---------------- fused flash attention over the concept pool ----------------
// Block = 768 threads = 12 waves = 4 q-tiles x 3 pool-slices. Each wave: 16
// q-rows, one third of the 256 pool tiles, independent online softmax, K/V
// fragments direct from global (L2/L3-resident). The per-tile barrier keeps
// the 4 q-waves of a slice on the same tile so L1/L2 dedup their identical
// K/V loads. 3-slice combine per q-tile in LDS at the end.
__global__ __launch_bounds__(768, 3) void k_attn(const unsigned short* __restrict__ Qg,
                                                 const unsigned short* __restrict__ poolKT,
                                                 const unsigned short* __restrict__ poolN,
                                                 unsigned short* __restrict__ agg){
  __shared__ float Mx[3][4][64][4];          // 12 KB cross-wave running-max exchange
  __shared__ float Racc[64][65];             // 16.25 KB combine buffer (65: bank-spread)
  __shared__ float Raccs[64][5];             // 1.25 KB row-sum combine
  __shared__ unsigned short P_lds[12][16*40];// 15 KB per-wave P round-trip (80B rows)

  int w = threadIdx.x >> 6, lane = threadIdx.x & 63;
  int qt = w & 3, slice = w >> 2;
  int lq = lane & 15, hq = lane >> 4;
  int qbase = blockIdx.x * 64 + qt * 16;

  const char* qb = (const char*)Qg;
  bf16x8 qf[8];
  #pragma unroll
  for (int kk = 0; kk < 8; ++kk)
    qf[kk] = ld_bf8(qb + (size_t)(qbase + lq) * 512 + kk*64 + hq*16);

  f32x4 acc[16];
  #pragma unroll
  for (int i = 0; i < 16; ++i) acc[i] = {};
  f32x4 accs = {};
  float m0 = -__builtin_inff(), m1 = -__builtin_inff(),
        m2 = -__builtin_inff(), m3 = -__builtin_inff();
  u16x8 ov;
  #pragma unroll
  for (int i = 0; i < 8; ++i) ov[i] = 0x3F80;   // bf16 1.0
  const bf16x8 ONES = __builtin_bit_cast(bf16x8, ov);

  const char* kb = (const char*)poolKT;
  const char* vb = (const char*)poolN;
  int t0 = (slice * 256) / 3, t1 = ((slice + 1) * 256) / 3;   // 85/85/86 tiles
  unsigned kbase = (unsigned)lq * 512u + (unsigned)hq * 16u;
  unsigned vbase = (unsigned)lq * 16384u + (unsigned)hq * 16u;
  unsigned short* Pw = &P_lds[w][0];

  for (int it = 0; it < 86; ++it) {
    int t = t0 + it;
    if (t < t1) {
      // S = Q @ K^T  -> 16 q rows x 32 p cols (direct-from-global K fragments)
      unsigned kof = (unsigned)t * 16384u + kbase;
      f32x4 s0 = {}, s1 = {};
      #pragma unroll
      for (int kk = 0; kk < 8; ++kk) {
        bf16x8 k0 = ld_bf8(kb + kof + kk*64);
        s0 = mfma16(qf[kk], k0, s0);
        bf16x8 k1 = ld_bf8(kb + kof + 8192u + kk*64);
        s1 = mfma16(qf[kk], k1, s1);
      }

      // online softmax: skip the lane-reduce + rescale when the max can't grow
      float p0 = fmaxf(s0[0], s1[0]), p1 = fmaxf(s0[1], s1[1]),
            p2 = fmaxf(s0[2], s1[2]), p3 = fmaxf(s0[3], s1[3]);
      bool ex = (p0 > m0) | (p1 > m1) | (p2 > m2) | (p3 > m3);
      if (__any((int)ex)) {
        #pragma unroll
        for (int msk = 1; msk < 16; msk <<= 1) {
          p0 = fmaxf(p0, __shfl_xor(p0, msk));
          p1 = fmaxf(p1, __shfl_xor(p1, msk));
          p2 = fmaxf(p2, __shfl_xor(p2, msk));
          p3 = fmaxf(p3, __shfl_xor(p3, msk));
        }
        float n0 = fmaxf(m0, p0), n1 = fmaxf(m1, p1),
              n2 = fmaxf(m2, p2), n3 = fmaxf(m3, p3);
        f32x4 sc;
        sc[0] = __expf(m0 - n0); sc[1] = __expf(m1 - n1);
        sc[2] = __expf(m2 - n2); sc[3] = __expf(m3 - n3);
        m0 = n0; m1 = n1; m2 = n2; m3 = n3;
        #pragma unroll
        for (int i = 0; i < 16; ++i) acc[i] *= sc;
        accs *= sc;
      }

      // P = exp(S - m), bf16, through this wave's padded LDS buffer (layout swap)
      {
        int q0 = hq * 4;
        Pw[(q0+0)*40 + lq]      = f2bf(__expf(s0[0] - m0));
        Pw[(q0+0)*40 + 16 + lq] = f2bf(__expf(s1[0] - m0));
        Pw[(q0+1)*40 + lq]      = f2bf(__expf(s0[1] - m1));
        Pw[(q0+1)*40 + 16 + lq] = f2bf(__expf(s1[1] - m1));
        Pw[(q0+2)*40 + lq]      = f2bf(__expf(s0[2] - m2));
        Pw[(q0+2)*40 + 16 + lq] = f2bf(__expf(s1[2] - m2));
        Pw[(q0+3)*40 + lq]      = f2bf(__expf(s0[3] - m3));
        Pw[(q0+3)*40 + 16 + lq] = f2bf(__expf(s1[3] - m3));
      }

      // PV: acc[q][f] += P[q][p] * V[p][f] (direct-from-global V fragments);
      // row-sum via ones-MFMA.  V row stride 16384 B -> fi*16 rows = fi*262144 B.
      bf16x8 pa = ld_bf8(&Pw[lq*40 + hq*8]);
      accs = mfma16(pa, ONES, accs);
      unsigned vof = vbase + (unsigned)t * 64u;
      #pragma unroll
      for (int fi = 0; fi < 16; ++fi) {
        bf16x8 vfrag = ld_bf8(vb + vof + (unsigned)fi * 262144u);
        acc[fi] = mfma16(pa, vfrag, acc[fi]);
      }
    }
    __syncthreads();   // keep the 4 q-waves of each slice on the same tile
  }

  // ---- per-q-tile combine of the 3 slice partials (m, accs, acc) ----
  Mx[slice][qt][lane][0] = m0; Mx[slice][qt][lane][1] = m1;
  Mx[slice][qt][lane][2] = m2; Mx[slice][qt][lane][3] = m3;
  __syncthreads();
  float M0 = fmaxf(fmaxf(Mx[0][qt][lane][0], Mx[1][qt][lane][0]), Mx[2][qt][lane][0]);
  float M1 = fmaxf(fmaxf(Mx[0][qt][lane][1], Mx[1][qt][lane][1]), Mx[2][qt][lane][1]);
  float M2 = fmaxf(fmaxf(Mx[0][qt][lane][2], Mx[1][qt][lane][2]), Mx[2][qt][lane][2]);
  float M3 = fmaxf(fmaxf(Mx[0][qt][lane][3], Mx[1][qt][lane][3]), Mx[2][qt][lane][3]);
  f32x4 sc;
  sc[0] = __expf(m0 - M0); sc[1] = __expf(m1 - M1);
  sc[2] = __expf(m2 - M2); sc[3] = __expf(m3 - M3);
  #pragma unroll
  for (int i = 0; i < 16; ++i) acc[i] *= sc;
  accs *= sc;

  for (int qq = 0; qq < 4; ++qq) {
    if (qt == qq && slice == 0) {
      #pragma unroll
      for (int fi = 0; fi < 16; ++fi)
        #pragma unroll
        for (int r = 0; r < 4; ++r) Racc[lane][fi*4 + r] = acc[fi][r];
      #pragma unroll
      for (int r = 0; r < 4; ++r) Raccs[lane][r] = accs[r];
    }
    __syncthreads();
    if (qt == qq && slice == 1) {
      #pragma unroll
      for (int fi = 0; fi < 16; ++fi)
        #pragma unroll
        for (int r = 0; r < 4; ++r) Racc[lane][fi*4 + r] += acc[fi][r];
      #pragma unroll
      for (int r = 0; r < 4; ++r) Raccs[lane][r] += accs[r];
    }
    __syncthreads();
    if (qt == qq && slice == 2) {
      #pragma unroll
      for (int fi = 0; fi < 16; ++fi)
        #pragma unroll
        for (int r = 0; r < 4; ++r) Racc[lane][fi*4 + r] += acc[fi][r];
      #pragma unroll
      for (int r = 0; r < 4; ++r) Raccs[lane][r] += accs[r];
    }
    __syncthreads();
    if (qt == qq) {
      // the 3 slice-waves of this q-tile store cooperatively
      int f0 = slice * 6, f1 = (slice == 2) ? 16 : slice * 6 + 6;
      for (int fi = f0; fi < f1; ++fi) {
        #pragma unroll
        for (int r = 0; r < 4; ++r) {
          float v = Racc[lane][fi*4 + r] / Raccs[lane][r];
          agg[(size_t)(qbase + hq*4 + r) * 256 + fi*16 + lq] = f2bf(v);
        }
      }
    }
    __syncthreads();   // before next qq reuses Racc
  }
}

// ---------------- output GEMM + gated residual ----------------
// out[n][c][l] = x[n][c][l] + gamma * sum_f wo[c][f] * agg[n*HW+l][f]
__global__ __launch_bounds__(256) void k_out(const float* __restrict__ x,
                                             const unsigned short* __restrict__ wo,
                                             const unsigned short* __restrict__ agg,
                                             const float* __restrict__ gammap,
                                             float* __restrict__ out){
  int w = threadIdx.x >> 6, lane = threadIdx.x & 63;
  int lq = lane & 15, hq = lane >> 4;
  int b = blockIdx.x;
  int lg = b & 63, cg = (b >> 6) & 7, n = b >> 9;
  const char* wb = (const char*)wo;
  const char* ab = (const char*)agg;
  f32x4 acc[4];
  #pragma unroll
  for (int i = 0; i < 4; ++i) acc[i] = {};
  int crow = cg*64 + w*16 + lq;
  #pragma unroll
  for (int kk = 0; kk < 8; ++kk) {
    bf16x8 a = ld_bf8(wb + (size_t)crow * 512 + kk*64 + hq*16);
    #pragma unroll
    for (int li = 0; li < 4; ++li) {
      bf16x8 bb = ld_bf8(ab + (size_t)(n*HWD + lg*64 + li*16 + lq) * 512 + kk*64 + hq*16);
      acc[li] = mfma16(a, bb, acc[li]);
    }
  }
  float g = gammap[0];
  #pragma unroll
  for (int li = 0; li < 4; ++li) {
    #pragma unroll
    for (int r = 0; r < 4; ++r) {
      int c = cg*64 + w*16 + hq*4 + r;
      int l = lg*64 + li*16 + lq;
      size_t idx = ((size_t)(n*CHN + c)) * HWD + l;
      out[idx] = x[idx] + g * acc[li][r];
    }
  }
}

extern "C" void kernel_launch(void* const* d_in, const int* in_sizes, int n_in,
                              void* d_out, int out_size, void* d_ws, size_t ws_size,
                              hipStream_t stream) {
  const float* x     = (const float*)d_in[0];
  const float* wt    = (const float*)d_in[1];
  const float* wo    = (const float*)d_in[2];
  const float* pool  = (const float*)d_in[3];
  const float* gamma = (const float*)d_in[4];
  char* ws = (char*)d_ws;
  unsigned short* wt_b  = (unsigned short*)(ws + 0);         // 256 KB
  unsigned short* wo_b  = (unsigned short*)(ws + 262144);    // 256 KB
  unsigned short* poolN = (unsigned short*)(ws + 524288);    // 4 MB
  unsigned short* poolKT= (unsigned short*)(ws + 4718592);   // 4 MB
  unsigned short* xT    = (unsigned short*)(ws + 8912896);   // 16 MB
  unsigned short* Qb    = (unsigned short*)(ws + 25690112);  // 8 MB
  unsigned short* aggb  = (unsigned short*)(ws + 34078720);  // 8 MB
  float* out = (float*)d_out;

  k_cvt<<<dim3(128), dim3(256), 0, stream>>>(wt, wt_b, 32768);
  k_cvt<<<dim3(128), dim3(256), 0, stream>>>(wo, wo_b, 32768);
  k_cvt<<<dim3(2048), dim3(256), 0, stream>>>(pool, poolN, 524288);
  k_poolT<<<dim3(2048), dim3(256), 0, stream>>>(pool, poolKT);
  k_xT<<<dim3(8192), dim3(256), 0, stream>>>(x, xT);
  k_theta<<<dim3(256), dim3(256), 0, stream>>>(xT, wt_b, Qb);
  k_attn<<<dim3(256), dim3(768), 0, stream>>>(Qb, poolKT, poolN, aggb);
  k_out<<<dim3(2048), dim3(256), 0, stream>>>(x, wo_b, aggb, gamma, out);
}

// Round 4
// 725.275 us; speedup vs baseline: 1.4169x; 1.4169x over previous
//
#include <hip/hip_runtime.h>

#define NB 4
#define CHN 512
#define HWD 4096
#define LTOT (NB*HWD)
#define FEAT_ 256
#define POOL_ 8192

typedef __attribute__((ext_vector_type(8))) __bf16 bf16x8;
typedef __attribute__((ext_vector_type(8))) unsigned short u16x8;
typedef __attribute__((ext_vector_type(4))) float f32x4;

static __device__ __forceinline__ unsigned short f2bf(float f){
  union { float f; unsigned u; } c; c.f = f;
  unsigned u = c.u;
  u += 0x7fffu + ((u >> 16) & 1u);   // round-to-nearest-even
  return (unsigned short)(u >> 16);
}

static __device__ __forceinline__ f32x4 mfma16(bf16x8 a, bf16x8 b, f32x4 c){
  return __builtin_amdgcn_mfma_f32_16x16x32_bf16(a, b, c, 0, 0, 0);
}

static __device__ __forceinline__ bf16x8 ld_bf8(const void* p){
  u16x8 v = *(const u16x8*)p;
  return __builtin_bit_cast(bf16x8, v);
}

static __device__ __forceinline__ void gload16(const void* g, void* l){
  __builtin_amdgcn_global_load_lds((const __attribute__((address_space(1))) void*)g,
                                   (__attribute__((address_space(3))) void*)l, 16, 0, 0);
}

// ---------------- f32 -> bf16 convert (layout-preserving) ----------------
__global__ void k_cvt(const float* __restrict__ src, unsigned short* __restrict__ dst, int n4){
  int i = blockIdx.x * 256 + threadIdx.x;
  if (i < n4) {
    const float4 v = *(const float4*)(src + (size_t)i * 4);
    ushort4 o; o.x = f2bf(v.x); o.y = f2bf(v.y); o.z = f2bf(v.z); o.w = f2bf(v.w);
    *(ushort4*)(dst + (size_t)i * 4) = o;
  }
}

// ---------------- pool [256][8192] f32 -> poolT_swz [8192][256] bf16 ----------------
// row p stored with byte_off(f) = (f*2) ^ ((p&7)<<4)  (pre-swizzled for linear
// global_load_lds staging; K_lds reads apply the same XOR)
__global__ __launch_bounds__(256) void k_poolT(const float* __restrict__ pool,
                                               unsigned short* __restrict__ poolT){
  __shared__ float tile[32][33];
  int bf = blockIdx.x & 7;
  int bp = blockIdx.x >> 3;
  int t = threadIdx.x;
  int fi = t >> 3, j = (t & 7) * 4;
  const float4 v = *(const float4*)(pool + (size_t)(bf*32 + fi) * POOL_ + bp*32 + j);
  tile[fi][j+0] = v.x; tile[fi][j+1] = v.y; tile[fi][j+2] = v.z; tile[fi][j+3] = v.w;
  __syncthreads();
  int pi = t >> 3, fj = (t & 7) * 4;
  int p = bp*32 + pi;
  ushort4 o;
  o.x = f2bf(tile[fj+0][pi]); o.y = f2bf(tile[fj+1][pi]);
  o.z = f2bf(tile[fj+2][pi]); o.w = f2bf(tile[fj+3][pi]);
  int fbyte = (bf*32 + fj) * 2;
  char* dst = (char*)poolT + (size_t)p * 512 + (fbyte ^ ((p & 7) << 4));
  *(ushort4*)dst = o;
}

// ---------------- x [4][512][4096] f32 -> xT [4][4096][512] bf16 ----------------
__global__ __launch_bounds__(256) void k_xT(const float* __restrict__ x,
                                            unsigned short* __restrict__ xT){
  __shared__ float tile[32][33];
  int b = blockIdx.x;
  int lt = b & 127; int ct = (b >> 7) & 15; int n = b >> 11;
  int t = threadIdx.x;
  int fi = t >> 3, j = (t & 7) * 4;
  const float4 v = *(const float4*)(x + ((size_t)(n*CHN + ct*32 + fi)) * HWD + lt*32 + j);
  tile[fi][j+0] = v.x; tile[fi][j+1] = v.y; tile[fi][j+2] = v.z; tile[fi][j+3] = v.w;
  __syncthreads();
  int pi = t >> 3, fj = (t & 7) * 4;
  ushort4 o;
  o.x = f2bf(tile[fj+0][pi]); o.y = f2bf(tile[fj+1][pi]);
  o.z = f2bf(tile[fj+2][pi]); o.w = f2bf(tile[fj+3][pi]);
  *(ushort4*)((char*)xT + ((size_t)(n*HWD + lt*32 + pi)) * 1024 + (ct*32 + fj) * 2) = o;
}

// ---------------- theta GEMM: Q[l][f] = sum_c xT[l][c] * wt[f][c] ----------------
__global__ __launch_bounds__(256) void k_theta(const unsigned short* __restrict__ xT,
                                               const unsigned short* __restrict__ wt,
                                               unsigned short* __restrict__ Q){
  int w = threadIdx.x >> 6, lane = threadIdx.x & 63;
  int lq = lane & 15, hq = lane >> 4;
  int lbase = blockIdx.x * 64 + w * 16;
  const char* xb = (const char*)xT;
  const char* wb = (const char*)wt;
  f32x4 acc[16];
  #pragma unroll
  for (int i = 0; i < 16; ++i) acc[i] = {};
  #pragma unroll 2
  for (int kk = 0; kk < 16; ++kk) {
    bf16x8 a = ld_bf8(xb + (size_t)(lbase + lq) * 1024 + kk*64 + hq*16);
    #pragma unroll
    for (int fi = 0; fi < 16; ++fi) {
      bf16x8 bfr = ld_bf8(wb + (size_t)(fi*16 + lq) * 1024 + kk*64 + hq*16);
      acc[fi] = mfma16(a, bfr, acc[fi]);
    }
  }
  #pragma unroll
  for (int fi = 0; fi < 16; ++fi) {
    #pragma unroll
    for (int r = 0; r < 4; ++r) {
      int l = lbase + hq*4 + r;
      Q[(size_t)l * 256 + fi*16 + lq] = f2bf(acc[fi][r]);
    }
  }
}

// ---------------- fused flash attention over the concept pool ----------------
// Grid 256 x 128 threads (2 waves). Each wave owns 32 q-rows (two 16-row
// A-fragments), so every K/V fragment read from LDS feeds two MFMAs.
// K/V double-buffered in LDS, staged via global_load_lds with counted
// vmcnt(18) + raw s_barrier (no full drain in the main loop).
__global__ __launch_bounds__(128) void k_attn(const unsigned short* __restrict__ Qg,
                                              const unsigned short* __restrict__ poolT,
                                              const unsigned short* __restrict__ poolN,
                                              unsigned short* __restrict__ agg){
  __shared__ unsigned short K_lds[2][32*256];   // 2 x 16 KB, XOR-swizzled rows
  __shared__ unsigned short V_lds[2][256*40];   // 2 x 20 KB, 80B-padded rows
  __shared__ unsigned short P_lds[2][2][16*40]; // [wave][qtile] P round-trip

  int w = threadIdx.x >> 6, lane = threadIdx.x & 63;
  int lq = lane & 15, hq = lane >> 4;
  int qa = blockIdx.x * 64 + w * 32;
  int qb = qa + 16;

  const char* qp = (const char*)Qg;
  bf16x8 qfa[8], qfb[8];
  #pragma unroll
  for (int kk = 0; kk < 8; ++kk) {
    qfa[kk] = ld_bf8(qp + (size_t)(qa + lq) * 512 + kk*64 + hq*16);
    qfb[kk] = ld_bf8(qp + (size_t)(qb + lq) * 512 + kk*64 + hq*16);
  }

  f32x4 accA[16], accB[16];
  #pragma unroll
  for (int i = 0; i < 16; ++i) { accA[i] = {}; accB[i] = {}; }
  f32x4 accsA = {}, accsB = {};
  float ma0 = -__builtin_inff(), ma1 = -__builtin_inff(),
        ma2 = -__builtin_inff(), ma3 = -__builtin_inff();
  float mb0 = -__builtin_inff(), mb1 = -__builtin_inff(),
        mb2 = -__builtin_inff(), mb3 = -__builtin_inff();
  u16x8 ov;
  #pragma unroll
  for (int i = 0; i < 8; ++i) ov[i] = 0x3F80;   // bf16 1.0
  const bf16x8 ONES = __builtin_bit_cast(bf16x8, ov);

  const char* ktb = (const char*)poolT;
  const char* vnb = (const char*)poolN;
  // per-lane staging addresses (t-independent parts)
  int kds[8]; const char* ksrc[8];
  #pragma unroll
  for (int i = 0; i < 8; ++i) {
    kds[i] = (w*8 + i) * 1024;
    ksrc[i] = ktb + kds[i] + lane*16;
  }
  int vds[10]; unsigned vsrc[10];
  #pragma unroll
  for (int i = 0; i < 10; ++i) {
    int byb = (w*10 + i) * 1024 + lane*16;
    vds[i] = (w*10 + i) * 1024;
    int vf = byb / 80;
    int r = byb - vf*80;
    if (r >= 64) r = 0;                 // pad region: harmless in-bounds read
    vsrc[i] = (unsigned)vf * 16384u + (unsigned)r;
  }
  int xorv = (lq & 7) << 3;             // ushort-index XOR = byte ((p&7)<<4)
  unsigned short* PwA = &P_lds[w][0][0];
  unsigned short* PwB = &P_lds[w][1][0];

  // prologue: stage tile 0 into buffer 0
  #pragma unroll
  for (int i = 0; i < 8; ++i)  gload16(ksrc[i], (char*)&K_lds[0][0] + kds[i]);
  #pragma unroll
  for (int i = 0; i < 10; ++i) gload16(vnb + vsrc[i], (char*)&V_lds[0][0] + vds[i]);

  int cur = 0;
  for (int t = 0; t < 256; ++t) {
    asm volatile("" ::: "memory");
    __builtin_amdgcn_s_barrier();       // all waves done reading buf cur^1
    asm volatile("" ::: "memory");
    if (t < 255) {
      int nt = t + 1;
      #pragma unroll
      for (int i = 0; i < 8; ++i)
        gload16(ksrc[i] + (size_t)nt*16384, (char*)&K_lds[cur^1][0] + kds[i]);
      #pragma unroll
      for (int i = 0; i < 10; ++i)
        gload16(vnb + vsrc[i] + (size_t)nt*64, (char*)&V_lds[cur^1][0] + vds[i]);
      asm volatile("s_waitcnt vmcnt(18)" ::: "memory");  // own tile-t loads done
    } else {
      asm volatile("s_waitcnt vmcnt(0)" ::: "memory");
    }
    __builtin_amdgcn_s_barrier();       // partner's tile-t loads done too
    asm volatile("" ::: "memory");

    const unsigned short* Kl = &K_lds[cur][0];
    const unsigned short* Vl = &V_lds[cur][0];

    // S = Q @ K^T : two q-tiles x 32 p-cols, K fragments reused for both
    f32x4 s0a = {}, s1a = {}, s0b = {}, s1b = {};
    #pragma unroll
    for (int kk = 0; kk < 8; ++kk) {
      int co = (kk*32 + hq*8) ^ xorv;
      bf16x8 k0 = ld_bf8(&Kl[lq*256 + co]);
      bf16x8 k1 = ld_bf8(&Kl[(16 + lq)*256 + co]);
      s0a = mfma16(qfa[kk], k0, s0a);
      s1a = mfma16(qfa[kk], k1, s1a);
      s0b = mfma16(qfb[kk], k0, s0b);
      s1b = mfma16(qfb[kk], k1, s1b);
    }

    // online softmax (shared skip-branch for both q-tiles)
    float pa0 = fmaxf(s0a[0], s1a[0]), pa1 = fmaxf(s0a[1], s1a[1]),
          pa2 = fmaxf(s0a[2], s1a[2]), pa3 = fmaxf(s0a[3], s1a[3]);
    float pb0 = fmaxf(s0b[0], s1b[0]), pb1 = fmaxf(s0b[1], s1b[1]),
          pb2 = fmaxf(s0b[2], s1b[2]), pb3 = fmaxf(s0b[3], s1b[3]);
    bool ex = (pa0 > ma0) | (pa1 > ma1) | (pa2 > ma2) | (pa3 > ma3) |
              (pb0 > mb0) | (pb1 > mb1) | (pb2 > mb2) | (pb3 > mb3);
    if (__any((int)ex)) {
      #pragma unroll
      for (int msk = 1; msk < 16; msk <<= 1) {
        pa0 = fmaxf(pa0, __shfl_xor(pa0, msk));
        pa1 = fmaxf(pa1, __shfl_xor(pa1, msk));
        pa2 = fmaxf(pa2, __shfl_xor(pa2, msk));
        pa3 = fmaxf(pa3, __shfl_xor(pa3, msk));
        pb0 = fmaxf(pb0, __shfl_xor(pb0, msk));
        pb1 = fmaxf(pb1, __shfl_xor(pb1, msk));
        pb2 = fmaxf(pb2, __shfl_xor(pb2, msk));
        pb3 = fmaxf(pb3, __shfl_xor(pb3, msk));
      }
      float na0 = fmaxf(ma0, pa0), na1 = fmaxf(ma1, pa1),
            na2 = fmaxf(ma2, pa2), na3 = fmaxf(ma3, pa3);
      float nb0 = fmaxf(mb0, pb0), nb1 = fmaxf(mb1, pb1),
            nb2 = fmaxf(mb2, pb2), nb3 = fmaxf(mb3, pb3);
      f32x4 scA, scB;
      scA[0] = __expf(ma0 - na0); scA[1] = __expf(ma1 - na1);
      scA[2] = __expf(ma2 - na2); scA[3] = __expf(ma3 - na3);
      scB[0] = __expf(mb0 - nb0); scB[1] = __expf(mb1 - nb1);
      scB[2] = __expf(mb2 - nb2); scB[3] = __expf(mb3 - nb3);
      ma0 = na0; ma1 = na1; ma2 = na2; ma3 = na3;
      mb0 = nb0; mb1 = nb1; mb2 = nb2; mb3 = nb3;
      #pragma unroll
      for (int i = 0; i < 16; ++i) { accA[i] *= scA; accB[i] *= scB; }
      accsA *= scA; accsB *= scB;
    }

    // P = exp(S - m) -> per-wave padded LDS buffers (layout swap)
    {
      int q0 = hq * 4;
      PwA[(q0+0)*40 + lq]      = f2bf(__expf(s0a[0] - ma0));
      PwA[(q0+0)*40 + 16 + lq] = f2bf(__expf(s1a[0] - ma0));
      PwA[(q0+1)*40 + lq]      = f2bf(__expf(s0a[1] - ma1));
      PwA[(q0+1)*40 + 16 + lq] = f2bf(__expf(s1a[1] - ma1));
      PwA[(q0+2)*40 + lq]      = f2bf(__expf(s0a[2] - ma2));
      PwA[(q0+2)*40 + 16 + lq] = f2bf(__expf(s1a[2] - ma2));
      PwA[(q0+3)*40 + lq]      = f2bf(__expf(s0a[3] - ma3));
      PwA[(q0+3)*40 + 16 + lq] = f2bf(__expf(s1a[3] - ma3));
      PwB[(q0+0)*40 + lq]      = f2bf(__expf(s0b[0] - mb0));
      PwB[(q0+0)*40 + 16 + lq] = f2bf(__expf(s1b[0] - mb0));
      PwB[(q0+1)*40 + lq]      = f2bf(__expf(s0b[1] - mb1));
      PwB[(q0+1)*40 + 16 + lq] = f2bf(__expf(s1b[1] - mb1));
      PwB[(q0+2)*40 + lq]      = f2bf(__expf(s0b[2] - mb2));
      PwB[(q0+2)*40 + 16 + lq] = f2bf(__expf(s1b[2] - mb2));
      PwB[(q0+3)*40 + lq]      = f2bf(__expf(s0b[3] - mb3));
      PwB[(q0+3)*40 + 16 + lq] = f2bf(__expf(s1b[3] - mb3));
    }

    // PV: each V fragment feeds both q-tiles; row-sums via ones-MFMA
    bf16x8 paA = ld_bf8(&PwA[lq*40 + hq*8]);
    bf16x8 paB = ld_bf8(&PwB[lq*40 + hq*8]);
    accsA = mfma16(paA, ONES, accsA);
    accsB = mfma16(paB, ONES, accsB);
    #pragma unroll
    for (int fi = 0; fi < 16; ++fi) {
      bf16x8 vfrag = ld_bf8(&Vl[(fi*16 + lq)*40 + hq*8]);
      accA[fi] = mfma16(paA, vfrag, accA[fi]);
      accB[fi] = mfma16(paB, vfrag, accB[fi]);
    }
    cur ^= 1;
  }

  f32x4 invA, invB;
  #pragma unroll
  for (int r = 0; r < 4; ++r) { invA[r] = 1.0f / accsA[r]; invB[r] = 1.0f / accsB[r]; }
  #pragma unroll
  for (int fi = 0; fi < 16; ++fi) {
    #pragma unroll
    for (int r = 0; r < 4; ++r) {
      agg[(size_t)(qa + hq*4 + r) * 256 + fi*16 + lq] = f2bf(accA[fi][r] * invA[r]);
      agg[(size_t)(qb + hq*4 + r) * 256 + fi*16 + lq] = f2bf(accB[fi][r] * invB[r]);
    }
  }
}

// ---------------- output GEMM + gated residual ----------------
// out[n][c][l] = x[n][c][l] + gamma * sum_f wo[c][f] * agg[n*HW+l][f]
__global__ __launch_bounds__(256) void k_out(const float* __restrict__ x,
                                             const unsigned short* __restrict__ wo,
                                             const unsigned short* __restrict__ agg,
                                             const float* __restrict__ gammap,
                                             float* __restrict__ out){
  int w = threadIdx.x >> 6, lane = threadIdx.x & 63;
  int lq = lane & 15, hq = lane >> 4;
  int b = blockIdx.x;
  int lg = b & 63, cg = (b >> 6) & 7, n = b >> 9;
  const char* wb = (const char*)wo;
  const char* ab = (const char*)agg;
  f32x4 acc[4];
  #pragma unroll
  for (int i = 0; i < 4; ++i) acc[i] = {};
  int crow = cg*64 + w*16 + lq;
  #pragma unroll
  for (int kk = 0; kk < 8; ++kk) {
    bf16x8 a = ld_bf8(wb + (size_t)crow * 512 + kk*64 + hq*16);
    #pragma unroll
    for (int li = 0; li < 4; ++li) {
      bf16x8 bb = ld_bf8(ab + (size_t)(n*HWD + lg*64 + li*16 + lq) * 512 + kk*64 + hq*16);
      acc[li] = mfma16(a, bb, acc[li]);
    }
  }
  float g = gammap[0];
  #pragma unroll
  for (int li = 0; li < 4; ++li) {
    #pragma unroll
    for (int r = 0; r < 4; ++r) {
      int c = cg*64 + w*16 + hq*4 + r;
      int l = lg*64 + li*16 + lq;
      size_t idx = ((size_t)(n*CHN + c)) * HWD + l;
      out[idx] = x[idx] + g * acc[li][r];
    }
  }
}

extern "C" void kernel_launch(void* const* d_in, const int* in_sizes, int n_in,
                              void* d_out, int out_size, void* d_ws, size_t ws_size,
                              hipStream_t stream) {
  const float* x     = (const float*)d_in[0];
  const float* wt    = (const float*)d_in[1];
  const float* wo    = (const float*)d_in[2];
  const float* pool  = (const float*)d_in[3];
  const float* gamma = (const float*)d_in[4];
  char* ws = (char*)d_ws;
  unsigned short* wt_b  = (unsigned short*)(ws + 0);         // 256 KB
  unsigned short* wo_b  = (unsigned short*)(ws + 262144);    // 256 KB
  unsigned short* poolN = (unsigned short*)(ws + 524288);    // 4 MB
  unsigned short* poolT = (unsigned short*)(ws + 4718592);   // 4 MB (swizzled)
  unsigned short* xT    = (unsigned short*)(ws + 8912896);   // 16 MB
  unsigned short* Qb    = (unsigned short*)(ws + 25690112);  // 8 MB
  unsigned short* aggb  = (unsigned short*)(ws + 34078720);  // 8 MB
  float* out = (float*)d_out;

  k_cvt<<<dim3(128), dim3(256), 0, stream>>>(wt, wt_b, 32768);
  k_cvt<<<dim3(128), dim3(256), 0, stream>>>(wo, wo_b, 32768);
  k_cvt<<<dim3(2048), dim3(256), 0, stream>>>(pool, poolN, 524288);
  k_poolT<<<dim3(2048), dim3(256), 0, stream>>>(pool, poolT);
  k_xT<<<dim3(8192), dim3(256), 0, stream>>>(x, xT);
  k_theta<<<dim3(256), dim3(256), 0, stream>>>(xT, wt_b, Qb);
  k_attn<<<dim3(256), dim3(128), 0, stream>>>(Qb, poolT, poolN, aggb);
  k_out<<<dim3(2048), dim3(256), 0, stream>>>(x, wo_b, aggb, gamma, out);
}

// Round 5
// 498.034 us; speedup vs baseline: 2.0634x; 1.4563x over previous
//
#include <hip/hip_runtime.h>

#define NB 4
#define CHN 512
#define HWD 4096
#define LTOT (NB*HWD)
#define FEAT_ 256
#define POOL_ 8192

typedef __attribute__((ext_vector_type(8))) __bf16 bf16x8;
typedef __attribute__((ext_vector_type(8))) unsigned short u16x8;
typedef __attribute__((ext_vector_type(8))) _Float16 f16x8;
typedef __attribute__((ext_vector_type(4))) float f32x4;

static __device__ __forceinline__ unsigned short f2bf(float f){
  union { float f; unsigned u; } c; c.f = f;
  unsigned u = c.u;
  u += 0x7fffu + ((u >> 16) & 1u);   // round-to-nearest-even
  return (unsigned short)(u >> 16);
}

static __device__ __forceinline__ f32x4 mfma16(bf16x8 a, bf16x8 b, f32x4 c){
  return __builtin_amdgcn_mfma_f32_16x16x32_bf16(a, b, c, 0, 0, 0);
}

static __device__ __forceinline__ bf16x8 ld_bf8(const void* p){
  u16x8 v = *(const u16x8*)p;
  return __builtin_bit_cast(bf16x8, v);
}

static __device__ __forceinline__ void gload16(const void* g, void* l){
  __builtin_amdgcn_global_load_lds((const __attribute__((address_space(1))) void*)g,
                                   (__attribute__((address_space(3))) void*)l, 16, 0, 0);
}

// ---------------- f32 -> bf16 convert (layout-preserving) ----------------
__global__ void k_cvt(const float* __restrict__ src, unsigned short* __restrict__ dst, int n4){
  int i = blockIdx.x * 256 + threadIdx.x;
  if (i < n4) {
    const float4 v = *(const float4*)(src + (size_t)i * 4);
    ushort4 o; o.x = f2bf(v.x); o.y = f2bf(v.y); o.z = f2bf(v.z); o.w = f2bf(v.w);
    *(ushort4*)(dst + (size_t)i * 4) = o;
  }
}

// ---------------- pool [256][8192] f32 -> poolT_swz [8192][256] bf16 ----------------
// row p stored with byte_off(f) = (f*2) ^ ((p&7)<<4)  (pre-swizzled for linear
// global_load_lds staging; K_lds reads apply the same XOR)
__global__ __launch_bounds__(256) void k_poolT(const float* __restrict__ pool,
                                               unsigned short* __restrict__ poolT){
  __shared__ float tile[32][33];
  int bf = blockIdx.x & 7;
  int bp = blockIdx.x >> 3;
  int t = threadIdx.x;
  int fi = t >> 3, j = (t & 7) * 4;
  const float4 v = *(const float4*)(pool + (size_t)(bf*32 + fi) * POOL_ + bp*32 + j);
  tile[fi][j+0] = v.x; tile[fi][j+1] = v.y; tile[fi][j+2] = v.z; tile[fi][j+3] = v.w;
  __syncthreads();
  int pi = t >> 3, fj = (t & 7) * 4;
  int p = bp*32 + pi;
  ushort4 o;
  o.x = f2bf(tile[fj+0][pi]); o.y = f2bf(tile[fj+1][pi]);
  o.z = f2bf(tile[fj+2][pi]); o.w = f2bf(tile[fj+3][pi]);
  int fbyte = (bf*32 + fj) * 2;
  char* dst = (char*)poolT + (size_t)p * 512 + (fbyte ^ ((p & 7) << 4));
  *(ushort4*)dst = o;
}

// ---------------- x [4][512][4096] f32 -> xT [4][4096][512] bf16 ----------------
__global__ __launch_bounds__(256) void k_xT(const float* __restrict__ x,
                                            unsigned short* __restrict__ xT){
  __shared__ float tile[32][33];
  int b = blockIdx.x;
  int lt = b & 127; int ct = (b >> 7) & 15; int n = b >> 11;
  int t = threadIdx.x;
  int fi = t >> 3, j = (t & 7) * 4;
  const float4 v = *(const float4*)(x + ((size_t)(n*CHN + ct*32 + fi)) * HWD + lt*32 + j);
  tile[fi][j+0] = v.x; tile[fi][j+1] = v.y; tile[fi][j+2] = v.z; tile[fi][j+3] = v.w;
  __syncthreads();
  int pi = t >> 3, fj = (t & 7) * 4;
  ushort4 o;
  o.x = f2bf(tile[fj+0][pi]); o.y = f2bf(tile[fj+1][pi]);
  o.z = f2bf(tile[fj+2][pi]); o.w = f2bf(tile[fj+3][pi]);
  *(ushort4*)((char*)xT + ((size_t)(n*HWD + lt*32 + pi)) * 1024 + (ct*32 + fj) * 2) = o;
}

// ---------------- theta GEMM: Q[l][f] = sum_c xT[l][c] * wt[f][c] ----------------
__global__ __launch_bounds__(256) void k_theta(const unsigned short* __restrict__ xT,
                                               const unsigned short* __restrict__ wt,
                                               unsigned short* __restrict__ Q){
  int w = threadIdx.x >> 6, lane = threadIdx.x & 63;
  int lq = lane & 15, hq = lane >> 4;
  int lbase = blockIdx.x * 64 + w * 16;
  const char* xb = (const char*)xT;
  const char* wb = (const char*)wt;
  f32x4 acc[16];
  #pragma unroll
  for (int i = 0; i < 16; ++i) acc[i] = {};
  #pragma unroll 2
  for (int kk = 0; kk < 16; ++kk) {
    bf16x8 a = ld_bf8(xb + (size_t)(lbase + lq) * 1024 + kk*64 + hq*16);
    #pragma unroll
    for (int fi = 0; fi < 16; ++fi) {
      bf16x8 bfr = ld_bf8(wb + (size_t)(fi*16 + lq) * 1024 + kk*64 + hq*16);
      acc[fi] = mfma16(a, bfr, acc[fi]);
    }
  }
  #pragma unroll
  for (int fi = 0; fi < 16; ++fi) {
    #pragma unroll
    for (int r = 0; r < 4; ++r) {
      int l = lbase + hq*4 + r;
      Q[(size_t)l * 256 + fi*16 + lq] = f2bf(acc[fi][r]);
    }
  }
}

// ---------------- fused flash attention over the concept pool ----------------
// Grid 1024 = 256 q-blocks x 4 pool-slices; block = 128 thr (2 waves x 32
// q-rows). Each block sweeps its 64-tile pool slice with K/V staged
// single-buffered into 37.9 KB LDS -> 4 blocks/CU = 8 waves/CU = 2/SIMD:
// cross-block TLP hides the stage/barrier stalls. Partials (f16 acc + f32
// m/sum) go to ws; k_comb merges the 4 slices.
__global__ __launch_bounds__(128) void k_attn(const unsigned short* __restrict__ Qg,
                                              const unsigned short* __restrict__ poolT,
                                              const unsigned short* __restrict__ poolN,
                                              _Float16* __restrict__ accP,
                                              float* __restrict__ pm,
                                              float* __restrict__ ps){
  __shared__ unsigned short K_lds[32*256];      // 16 KB: [32 p][256 f] XOR-swizzled rows
  __shared__ unsigned short V_lds[4*256*8];     // 16 KB: [pc=4][f=256][pj=8] subtiles
  __shared__ unsigned short P_lds[2][2][16*40]; //  5 KB: [wave][qtile] P round-trip

  int w = threadIdx.x >> 6, lane = threadIdx.x & 63;
  int lq = lane & 15, hq = lane >> 4;
  int qblock = blockIdx.x & 255, slice = blockIdx.x >> 8;
  int qa = qblock * 64 + w * 32;
  int qb = qa + 16;

  const char* qp = (const char*)Qg;
  bf16x8 qfa[8], qfb[8];
  #pragma unroll
  for (int kk = 0; kk < 8; ++kk) {
    qfa[kk] = ld_bf8(qp + (size_t)(qa + lq) * 512 + kk*64 + hq*16);
    qfb[kk] = ld_bf8(qp + (size_t)(qb + lq) * 512 + kk*64 + hq*16);
  }

  f32x4 accA[16], accB[16];
  #pragma unroll
  for (int i = 0; i < 16; ++i) { accA[i] = {}; accB[i] = {}; }
  f32x4 accsA = {}, accsB = {};
  float ma0 = -__builtin_inff(), ma1 = -__builtin_inff(),
        ma2 = -__builtin_inff(), ma3 = -__builtin_inff();
  float mb0 = -__builtin_inff(), mb1 = -__builtin_inff(),
        mb2 = -__builtin_inff(), mb3 = -__builtin_inff();
  u16x8 ov;
  #pragma unroll
  for (int i = 0; i < 8; ++i) ov[i] = 0x3F80;   // bf16 1.0
  const bf16x8 ONES = __builtin_bit_cast(bf16x8, ov);

  const char* ktb = (const char*)poolT;
  const char* vnb = (const char*)poolN;
  // K staging: dst base (w*8+i)*1024 (wave-uniform), src = same + lane*16
  // V staging: chunks c = i*128 + w*64 + lane; LDS byte c*16;
  //   src = poolN + (fb+lane)*16384 + tt*64 + pc*16,  cw=2i+w, pc=cw>>2, fb=(cw&3)*64
  size_t vsrcl[8]; int vdst[8];
  #pragma unroll
  for (int i = 0; i < 8; ++i) {
    int cw = 2*i + w;
    int pc = cw >> 2, fb = (cw & 3) * 64;
    vdst[i] = cw * 1024;
    vsrcl[i] = (size_t)(fb + lane) * 16384 + (size_t)pc * 16;
  }
  int xorv = (lq & 7) << 3;             // ushort-index XOR = byte ((p&7)<<4)
  unsigned short* PwA = &P_lds[w][0][0];
  unsigned short* PwB = &P_lds[w][1][0];

  for (int t = 0; t < 64; ++t) {
    int tt = slice * 64 + t;
    __syncthreads();                    // all waves done reading previous tile
    #pragma unroll
    for (int i = 0; i < 8; ++i)
      gload16(ktb + (size_t)tt*16384 + (w*8 + i)*1024 + lane*16,
              (char*)K_lds + (w*8 + i)*1024);
    #pragma unroll
    for (int i = 0; i < 8; ++i)
      gload16(vnb + vsrcl[i] + (size_t)tt*64, (char*)V_lds + vdst[i]);
    __syncthreads();                    // drains vmcnt(0), then barrier

    // S = Q @ K^T : two q-tiles x 32 p-cols, K fragments reused for both
    f32x4 s0a = {}, s1a = {}, s0b = {}, s1b = {};
    #pragma unroll
    for (int kk = 0; kk < 8; ++kk) {
      int co = (kk*32 + hq*8) ^ xorv;
      bf16x8 k0 = ld_bf8(&K_lds[lq*256 + co]);
      bf16x8 k1 = ld_bf8(&K_lds[(16 + lq)*256 + co]);
      s0a = mfma16(qfa[kk], k0, s0a);
      s1a = mfma16(qfa[kk], k1, s1a);
      s0b = mfma16(qfb[kk], k0, s0b);
      s1b = mfma16(qfb[kk], k1, s1b);
    }

    // online softmax (shared skip-branch for both q-tiles)
    float pa0 = fmaxf(s0a[0], s1a[0]), pa1 = fmaxf(s0a[1], s1a[1]),
          pa2 = fmaxf(s0a[2], s1a[2]), pa3 = fmaxf(s0a[3], s1a[3]);
    float pb0 = fmaxf(s0b[0], s1b[0]), pb1 = fmaxf(s0b[1], s1b[1]),
          pb2 = fmaxf(s0b[2], s1b[2]), pb3 = fmaxf(s0b[3], s1b[3]);
    bool ex = (pa0 > ma0) | (pa1 > ma1) | (pa2 > ma2) | (pa3 > ma3) |
              (pb0 > mb0) | (pb1 > mb1) | (pb2 > mb2) | (pb3 > mb3);
    if (__any((int)ex)) {
      #pragma unroll
      for (int msk = 1; msk < 16; msk <<= 1) {
        pa0 = fmaxf(pa0, __shfl_xor(pa0, msk));
        pa1 = fmaxf(pa1, __shfl_xor(pa1, msk));
        pa2 = fmaxf(pa2, __shfl_xor(pa2, msk));
        pa3 = fmaxf(pa3, __shfl_xor(pa3, msk));
        pb0 = fmaxf(pb0, __shfl_xor(pb0, msk));
        pb1 = fmaxf(pb1, __shfl_xor(pb1, msk));
        pb2 = fmaxf(pb2, __shfl_xor(pb2, msk));
        pb3 = fmaxf(pb3, __shfl_xor(pb3, msk));
      }
      float na0 = fmaxf(ma0, pa0), na1 = fmaxf(ma1, pa1),
            na2 = fmaxf(ma2, pa2), na3 = fmaxf(ma3, pa3);
      float nb0 = fmaxf(mb0, pb0), nb1 = fmaxf(mb1, pb1),
            nb2 = fmaxf(mb2, pb2), nb3 = fmaxf(mb3, pb3);
      f32x4 scA, scB;
      scA[0] = __expf(ma0 - na0); scA[1] = __expf(ma1 - na1);
      scA[2] = __expf(ma2 - na2); scA[3] = __expf(ma3 - na3);
      scB[0] = __expf(mb0 - nb0); scB[1] = __expf(mb1 - nb1);
      scB[2] = __expf(mb2 - nb2); scB[3] = __expf(mb3 - nb3);
      ma0 = na0; ma1 = na1; ma2 = na2; ma3 = na3;
      mb0 = nb0; mb1 = nb1; mb2 = nb2; mb3 = nb3;
      #pragma unroll
      for (int i = 0; i < 16; ++i) { accA[i] *= scA; accB[i] *= scB; }
      accsA *= scA; accsB *= scB;
    }

    // P = exp(S - m) -> per-wave padded LDS buffers (layout swap)
    {
      int q0 = hq * 4;
      PwA[(q0+0)*40 + lq]      = f2bf(__expf(s0a[0] - ma0));
      PwA[(q0+0)*40 + 16 + lq] = f2bf(__expf(s1a[0] - ma0));
      PwA[(q0+1)*40 + lq]      = f2bf(__expf(s0a[1] - ma1));
      PwA[(q0+1)*40 + 16 + lq] = f2bf(__expf(s1a[1] - ma1));
      PwA[(q0+2)*40 + lq]      = f2bf(__expf(s0a[2] - ma2));
      PwA[(q0+2)*40 + 16 + lq] = f2bf(__expf(s1a[2] - ma2));
      PwA[(q0+3)*40 + lq]      = f2bf(__expf(s0a[3] - ma3));
      PwA[(q0+3)*40 + 16 + lq] = f2bf(__expf(s1a[3] - ma3));
      PwB[(q0+0)*40 + lq]      = f2bf(__expf(s0b[0] - mb0));
      PwB[(q0+0)*40 + 16 + lq] = f2bf(__expf(s1b[0] - mb0));
      PwB[(q0+1)*40 + lq]      = f2bf(__expf(s0b[1] - mb1));
      PwB[(q0+1)*40 + 16 + lq] = f2bf(__expf(s1b[1] - mb1));
      PwB[(q0+2)*40 + lq]      = f2bf(__expf(s0b[2] - mb2));
      PwB[(q0+2)*40 + 16 + lq] = f2bf(__expf(s1b[2] - mb2));
      PwB[(q0+3)*40 + lq]      = f2bf(__expf(s0b[3] - mb3));
      PwB[(q0+3)*40 + 16 + lq] = f2bf(__expf(s1b[3] - mb3));
    }

    // PV: each V fragment feeds both q-tiles; row-sums via ones-MFMA.
    // V fragment: V[p=hq*8+j][f=fi*16+lq] = V_lds[hq][fi*16+lq][j]
    bf16x8 paA = ld_bf8(&PwA[lq*40 + hq*8]);
    bf16x8 paB = ld_bf8(&PwB[lq*40 + hq*8]);
    accsA = mfma16(paA, ONES, accsA);
    accsB = mfma16(paB, ONES, accsB);
    #pragma unroll
    for (int fi = 0; fi < 16; ++fi) {
      bf16x8 vfrag = ld_bf8(&V_lds[hq*2048 + (fi*16 + lq)*8]);
      accA[fi] = mfma16(paA, vfrag, accA[fi]);
      accB[fi] = mfma16(paB, vfrag, accB[fi]);
    }
  }

  // ---- store partials (f16 acc, f32 m / rowsum) for k_comb ----
  size_t base = (size_t)slice * 16384;
  #pragma unroll
  for (int fi = 0; fi < 16; ++fi) {
    #pragma unroll
    for (int r = 0; r < 4; ++r) {
      accP[(base + qa + hq*4 + r) * 256 + fi*16 + lq] = (_Float16)accA[fi][r];
      accP[(base + qb + hq*4 + r) * 256 + fi*16 + lq] = (_Float16)accB[fi][r];
    }
  }
  if (lq == 0) {
    pm[base + qa + hq*4 + 0] = ma0; ps[base + qa + hq*4 + 0] = accsA[0];
    pm[base + qa + hq*4 + 1] = ma1; ps[base + qa + hq*4 + 1] = accsA[1];
    pm[base + qa + hq*4 + 2] = ma2; ps[base + qa + hq*4 + 2] = accsA[2];
    pm[base + qa + hq*4 + 3] = ma3; ps[base + qa + hq*4 + 3] = accsA[3];
    pm[base + qb + hq*4 + 0] = mb0; ps[base + qb + hq*4 + 0] = accsB[0];
    pm[base + qb + hq*4 + 1] = mb1; ps[base + qb + hq*4 + 1] = accsB[1];
    pm[base + qb + hq*4 + 2] = mb2; ps[base + qb + hq*4 + 2] = accsB[2];
    pm[base + qb + hq*4 + 3] = mb3; ps[base + qb + hq*4 + 3] = accsB[3];
  }
}

// ---------------- combine the 4 pool-slice partials ----------------
__global__ __launch_bounds__(256) void k_comb(const _Float16* __restrict__ accP,
                                              const float* __restrict__ pm,
                                              const float* __restrict__ ps,
                                              unsigned short* __restrict__ agg){
  int q = blockIdx.x * 16 + (threadIdx.x >> 4);
  int f0 = (threadIdx.x & 15) * 16;
  float m0 = pm[q], m1 = pm[16384 + q], m2 = pm[2*16384 + q], m3 = pm[3*16384 + q];
  float M = fmaxf(fmaxf(m0, m1), fmaxf(m2, m3));
  float w0 = __expf(m0 - M), w1 = __expf(m1 - M),
        w2 = __expf(m2 - M), w3 = __expf(m3 - M);
  float denom = w0*ps[q] + w1*ps[16384 + q] + w2*ps[2*16384 + q] + w3*ps[3*16384 + q];
  float inv = 1.0f / denom;
  const _Float16* a0 = accP + (size_t)q * 256 + f0;
  #pragma unroll
  for (int j = 0; j < 16; j += 8) {
    f16x8 v0 = *(const f16x8*)(a0 + j);
    f16x8 v1 = *(const f16x8*)(a0 + j + (size_t)16384*256);
    f16x8 v2 = *(const f16x8*)(a0 + j + (size_t)2*16384*256);
    f16x8 v3 = *(const f16x8*)(a0 + j + (size_t)3*16384*256);
    u16x8 o;
    #pragma unroll
    for (int k = 0; k < 8; ++k) {
      float s = w0*(float)v0[k] + w1*(float)v1[k] + w2*(float)v2[k] + w3*(float)v3[k];
      o[k] = f2bf(s * inv);
    }
    *(u16x8*)(agg + (size_t)q * 256 + f0 + j) = o;
  }
}

// ---------------- output GEMM + gated residual ----------------
// out[n][c][l] = x[n][c][l] + gamma * sum_f wo[c][f] * agg[n*HW+l][f]
__global__ __launch_bounds__(256) void k_out(const float* __restrict__ x,
                                             const unsigned short* __restrict__ wo,
                                             const unsigned short* __restrict__ agg,
                                             const float* __restrict__ gammap,
                                             float* __restrict__ out){
  int w = threadIdx.x >> 6, lane = threadIdx.x & 63;
  int lq = lane & 15, hq = lane >> 4;
  int b = blockIdx.x;
  int lg = b & 63, cg = (b >> 6) & 7, n = b >> 9;
  const char* wb = (const char*)wo;
  const char* ab = (const char*)agg;
  f32x4 acc[4];
  #pragma unroll
  for (int i = 0; i < 4; ++i) acc[i] = {};
  int crow = cg*64 + w*16 + lq;
  #pragma unroll
  for (int kk = 0; kk < 8; ++kk) {
    bf16x8 a = ld_bf8(wb + (size_t)crow * 512 + kk*64 + hq*16);
    #pragma unroll
    for (int li = 0; li < 4; ++li) {
      bf16x8 bb = ld_bf8(ab + (size_t)(n*HWD + lg*64 + li*16 + lq) * 512 + kk*64 + hq*16);
      acc[li] = mfma16(a, bb, acc[li]);
    }
  }
  float g = gammap[0];
  #pragma unroll
  for (int li = 0; li < 4; ++li) {
    #pragma unroll
    for (int r = 0; r < 4; ++r) {
      int c = cg*64 + w*16 + hq*4 + r;
      int l = lg*64 + li*16 + lq;
      size_t idx = ((size_t)(n*CHN + c)) * HWD + l;
      out[idx] = x[idx] + g * acc[li][r];
    }
  }
}

extern "C" void kernel_launch(void* const* d_in, const int* in_sizes, int n_in,
                              void* d_out, int out_size, void* d_ws, size_t ws_size,
                              hipStream_t stream) {
  const float* x     = (const float*)d_in[0];
  const float* wt    = (const float*)d_in[1];
  const float* wo    = (const float*)d_in[2];
  const float* pool  = (const float*)d_in[3];
  const float* gamma = (const float*)d_in[4];
  char* ws = (char*)d_ws;
  unsigned short* wt_b  = (unsigned short*)(ws + 0);         // 256 KB
  unsigned short* wo_b  = (unsigned short*)(ws + 262144);    // 256 KB
  unsigned short* poolN = (unsigned short*)(ws + 524288);    // 4 MB
  unsigned short* poolT = (unsigned short*)(ws + 4718592);   // 4 MB (swizzled)
  unsigned short* Qb    = (unsigned short*)(ws + 8912896);   // 8 MB
  unsigned short* aggb  = (unsigned short*)(ws + 17301504);  // 8 MB
  unsigned short* xT    = (unsigned short*)(ws + 25690112);  // 16 MB (dead after k_theta)
  _Float16*       accP  = (_Float16*)(ws + 25690112);        // 32 MB (overlaps dead xT)
  float*          pm    = (float*)(ws + 59244544);           // 256 KB
  float*          ps    = (float*)(ws + 59506688);           // 256 KB -> 59.8 MB total
  float* out = (float*)d_out;

  k_cvt<<<dim3(128), dim3(256), 0, stream>>>(wt, wt_b, 32768);
  k_cvt<<<dim3(128), dim3(256), 0, stream>>>(wo, wo_b, 32768);
  k_cvt<<<dim3(2048), dim3(256), 0, stream>>>(pool, poolN, 524288);
  k_poolT<<<dim3(2048), dim3(256), 0, stream>>>(pool, poolT);
  k_xT<<<dim3(8192), dim3(256), 0, stream>>>(x, xT);
  k_theta<<<dim3(256), dim3(256), 0, stream>>>(xT, wt_b, Qb);
  k_attn<<<dim3(1024), dim3(128), 0, stream>>>(Qb, poolT, poolN, accP, pm, ps);
  k_comb<<<dim3(1024), dim3(256), 0, stream>>>(accP, pm, ps, aggb);
  k_out<<<dim3(2048), dim3(256), 0, stream>>>(x, wo_b, aggb, gamma, out);
}